// Round 1
// baseline (331.224 us; speedup 1.0000x reference)
//
#include <hip/hip_runtime.h>
#include <hip/hip_bf16.h>

typedef __bf16 bf16x8 __attribute__((ext_vector_type(8)));
typedef float f32x4 __attribute__((ext_vector_type(4)));
typedef unsigned short u16;

__device__ __forceinline__ u16 f2b(float x) {
  __hip_bfloat16 h = __float2bfloat16(x);
  return __builtin_bit_cast(u16, h);
}

// ---------------- cast f32 -> bf16 (4 elems/thread) ----------------
__global__ __launch_bounds__(256) void cast_bf16_kernel(const float* __restrict__ src,
                                                        u16* __restrict__ dst, int n4) {
  int i = blockIdx.x * 256 + threadIdx.x;
  if (i >= n4) return;
  float4 v = ((const float4*)src)[i];
  ushort4 o;
  o.x = f2b(v.x); o.y = f2b(v.y); o.z = f2b(v.z); o.w = f2b(v.w);
  ((ushort4*)dst)[i] = o;
}

// ---------------- transpose+cast: src [R][C] f32 -> dst [C][R] bf16 ----------------
__global__ __launch_bounds__(256) void transpose_cast_kernel(const float* __restrict__ src,
                                                             u16* __restrict__ dst,
                                                             int R, int C) {
  __shared__ float t[32][33];
  int c0 = blockIdx.x * 32, r0 = blockIdx.y * 32;
  int tx = threadIdx.x, ty = threadIdx.y;
  for (int k = 0; k < 32; k += 8)
    t[ty + k][tx] = src[(size_t)(r0 + ty + k) * C + c0 + tx];
  __syncthreads();
  for (int k = 0; k < 32; k += 8)
    dst[(size_t)(c0 + ty + k) * R + r0 + tx] = f2b(t[tx][ty + k]);
}

// ---------------- QKV GEMM: xb[4096][1024] @ Wqkv_t[3072][1024]^T ----------------
// 128x128 tile, BK=32, 4 waves (2x2), each wave 64x64 (4x4 frags of 16x16x32).
// Epilogue scatters into Qb/Kb [B][H][N][64] and Vt [B][H][64][N].
__global__ __launch_bounds__(256) void gemm_qkv_kernel(const u16* __restrict__ A,
                                                       const u16* __restrict__ Bt,
                                                       u16* __restrict__ Qb,
                                                       u16* __restrict__ Kb,
                                                       u16* __restrict__ Vt) {
  __shared__ u16 lA[128 * 32], lB[128 * 32];
  const int tid = threadIdx.x, lane = tid & 63, w = tid >> 6;
  const int wr = w >> 1, wc = w & 1, lrow = lane & 15, lk = lane >> 4;
  const int bm = blockIdx.y, bn = blockIdx.x;
  const int srow = tid >> 2, scol = (tid & 3) * 8;
  const u16* Arow = A + (size_t)(bm * 128 + srow) * 1024 + scol;
  const u16* Brow = Bt + (size_t)(bn * 128 + srow) * 1024 + scol;
  f32x4 acc[4][4] = {};
  for (int k0 = 0; k0 < 1024; k0 += 32) {
    uint4 a0 = *(const uint4*)(Arow + k0);
    uint4 a1 = *(const uint4*)(Arow + 64 * 1024 + k0);
    uint4 b0 = *(const uint4*)(Brow + k0);
    uint4 b1 = *(const uint4*)(Brow + 64 * 1024 + k0);
    __syncthreads();
    *(uint4*)&lA[srow * 32 + scol] = a0;
    *(uint4*)&lA[(srow + 64) * 32 + scol] = a1;
    *(uint4*)&lB[srow * 32 + scol] = b0;
    *(uint4*)&lB[(srow + 64) * 32 + scol] = b1;
    __syncthreads();
    bf16x8 af[4], bfr[4];
    for (int mi = 0; mi < 4; mi++)
      af[mi] = *(const bf16x8*)&lA[(wr * 64 + mi * 16 + lrow) * 32 + lk * 8];
    for (int ni = 0; ni < 4; ni++)
      bfr[ni] = *(const bf16x8*)&lB[(wc * 64 + ni * 16 + lrow) * 32 + lk * 8];
    for (int mi = 0; mi < 4; mi++)
      for (int ni = 0; ni < 4; ni++)
        acc[mi][ni] = __builtin_amdgcn_mfma_f32_16x16x32_bf16(af[mi], bfr[ni], acc[mi][ni], 0, 0, 0);
  }
  const int rowbase = bm * 128 + wr * 64;
  const int colbase = bn * 128 + wc * 64;
  for (int mi = 0; mi < 4; mi++)
    for (int ni = 0; ni < 4; ni++)
      for (int r = 0; r < 4; r++) {
        int row = rowbase + mi * 16 + lk * 4 + r;
        int col = colbase + ni * 16 + lrow;
        int b = row >> 11, n = row & 2047;
        int which = col >> 10, within = col & 1023;
        int h = within >> 6, d = within & 63;
        u16 v = f2b(acc[mi][ni][r]);
        size_t bh = (size_t)(b * 16 + h);
        if (which == 0)      Qb[(bh * 2048 + n) * 64 + d] = v;
        else if (which == 1) Kb[(bh * 2048 + n) * 64 + d] = v;
        else                 Vt[(bh * 64 + d) * 2048 + n] = v;
      }
}

// ---------------- out-proj GEMM: attnb[4096][1024] @ Wout_t[1024][1024]^T + bias ----------------
__global__ __launch_bounds__(256) void gemm_out_kernel(const u16* __restrict__ A,
                                                       const u16* __restrict__ Bt,
                                                       const float* __restrict__ bias,
                                                       float* __restrict__ out) {
  __shared__ u16 lA[128 * 32], lB[128 * 32];
  const int tid = threadIdx.x, lane = tid & 63, w = tid >> 6;
  const int wr = w >> 1, wc = w & 1, lrow = lane & 15, lk = lane >> 4;
  const int bm = blockIdx.y, bn = blockIdx.x;
  const int srow = tid >> 2, scol = (tid & 3) * 8;
  const u16* Arow = A + (size_t)(bm * 128 + srow) * 1024 + scol;
  const u16* Brow = Bt + (size_t)(bn * 128 + srow) * 1024 + scol;
  f32x4 acc[4][4] = {};
  for (int k0 = 0; k0 < 1024; k0 += 32) {
    uint4 a0 = *(const uint4*)(Arow + k0);
    uint4 a1 = *(const uint4*)(Arow + 64 * 1024 + k0);
    uint4 b0 = *(const uint4*)(Brow + k0);
    uint4 b1 = *(const uint4*)(Brow + 64 * 1024 + k0);
    __syncthreads();
    *(uint4*)&lA[srow * 32 + scol] = a0;
    *(uint4*)&lA[(srow + 64) * 32 + scol] = a1;
    *(uint4*)&lB[srow * 32 + scol] = b0;
    *(uint4*)&lB[(srow + 64) * 32 + scol] = b1;
    __syncthreads();
    bf16x8 af[4], bfr[4];
    for (int mi = 0; mi < 4; mi++)
      af[mi] = *(const bf16x8*)&lA[(wr * 64 + mi * 16 + lrow) * 32 + lk * 8];
    for (int ni = 0; ni < 4; ni++)
      bfr[ni] = *(const bf16x8*)&lB[(wc * 64 + ni * 16 + lrow) * 32 + lk * 8];
    for (int mi = 0; mi < 4; mi++)
      for (int ni = 0; ni < 4; ni++)
        acc[mi][ni] = __builtin_amdgcn_mfma_f32_16x16x32_bf16(af[mi], bfr[ni], acc[mi][ni], 0, 0, 0);
  }
  const int rowbase = bm * 128 + wr * 64;
  const int colbase = bn * 128 + wc * 64;
  for (int mi = 0; mi < 4; mi++)
    for (int ni = 0; ni < 4; ni++)
      for (int r = 0; r < 4; r++) {
        int row = rowbase + mi * 16 + lk * 4 + r;
        int col = colbase + ni * 16 + lrow;
        out[(size_t)row * 1024 + col] = acc[mi][ni][r] + bias[col];
      }
}

// ---------------- flash attention ----------------
// grid: (N/64, B*H). 4 waves/block; wave w owns 16 q-rows. KV chunks of 32.
__global__ __launch_bounds__(256) void attn_kernel(const u16* __restrict__ Qb,
                                                   const u16* __restrict__ Kb,
                                                   const u16* __restrict__ Vt,
                                                   const int* __restrict__ mask,
                                                   u16* __restrict__ attnb) {
  __shared__ u16 Plds[4][16 * 32];
  const int tid = threadIdx.x, lane = tid & 63, w = tid >> 6;
  const int lrow = lane & 15, lk = lane >> 4;
  const int qt = blockIdx.x, bh = blockIdx.y;
  const int h = bh & 15, b = bh >> 4;
  const int q0 = qt * 64 + w * 16;
  const u16* Qp = Qb + (size_t)bh * 2048 * 64;
  const u16* Kp = Kb + (size_t)bh * 2048 * 64;
  const u16* Vp = Vt + (size_t)bh * 64 * 2048;
  u16* myP = &Plds[w][0];

  bf16x8 qf0 = *(const bf16x8*)&Qp[(q0 + lrow) * 64 + lk * 8];
  bf16x8 qf1 = *(const bf16x8*)&Qp[(q0 + lrow) * 64 + 32 + lk * 8];

  f32x4 acc[4] = {};
  float m[4], lsum[4];
  for (int r = 0; r < 4; r++) { m[r] = -3.0e38f; lsum[r] = 0.f; }

  for (int j0 = 0; j0 < 2048; j0 += 32) {
    // ---- S = Q K^T for 16x32 chunk (two 16x16 tiles) ----
    f32x4 s[2];
    for (int jc = 0; jc < 2; jc++) {
      const u16* kbase = &Kp[(j0 + jc * 16 + lrow) * 64 + lk * 8];
      bf16x8 kf0 = *(const bf16x8*)kbase;
      bf16x8 kf1 = *(const bf16x8*)(kbase + 32);
      f32x4 z = {};
      z = __builtin_amdgcn_mfma_f32_16x16x32_bf16(qf0, kf0, z, 0, 0, 0);
      z = __builtin_amdgcn_mfma_f32_16x16x32_bf16(qf1, kf1, z, 0, 0, 0);
      s[jc] = z;
    }
    // ---- scale + mask + row-max ----
    float pmax[4] = {-3.0e38f, -3.0e38f, -3.0e38f, -3.0e38f};
    for (int jc = 0; jc < 2; jc++)
      for (int r = 0; r < 4; r++) {
        int qrow = q0 + lk * 4 + r;
        int jcol = j0 + jc * 16 + lrow;
        float v = s[jc][r] * 0.125f;
        if (mask[(size_t)qrow * 2048 + jcol] == 0) v = -1e9f;
        s[jc][r] = v;
        pmax[r] = fmaxf(pmax[r], v);
      }
    for (int off = 1; off < 16; off <<= 1)
      for (int r = 0; r < 4; r++)
        pmax[r] = fmaxf(pmax[r], __shfl_xor(pmax[r], off, 64));
    // ---- online softmax update ----
    float f[4], psum[4];
    for (int r = 0; r < 4; r++) {
      float mn = fmaxf(m[r], pmax[r]);
      f[r] = __expf(m[r] - mn);
      m[r] = mn;
      psum[r] = 0.f;
    }
    for (int jc = 0; jc < 2; jc++)
      for (int r = 0; r < 4; r++) {
        float p = __expf(s[jc][r] - m[r]);
        psum[r] += p;
        myP[(lk * 4 + r) * 32 + jc * 16 + lrow] = f2b(p);
      }
    for (int off = 1; off < 16; off <<= 1)
      for (int r = 0; r < 4; r++)
        psum[r] += __shfl_xor(psum[r], off, 64);
    for (int r = 0; r < 4; r++) lsum[r] = lsum[r] * f[r] + psum[r];
    for (int dt = 0; dt < 4; dt++)
      for (int r = 0; r < 4; r++) acc[dt][r] *= f[r];
    // drain wave's LDS writes; clobber orders the ds ops (same-wave LDS is HW-ordered)
    asm volatile("s_waitcnt lgkmcnt(0)" ::: "memory");
    // ---- PV: A-frag from LDS P, B-frag from Vt (contiguous in j) ----
    bf16x8 pf = *(const bf16x8*)&myP[lrow * 32 + lk * 8];
    for (int dt = 0; dt < 4; dt++) {
      bf16x8 vf = *(const bf16x8*)&Vp[(dt * 16 + lrow) * 2048 + j0 + lk * 8];
      acc[dt] = __builtin_amdgcn_mfma_f32_16x16x32_bf16(pf, vf, acc[dt], 0, 0, 0);
    }
  }
  // ---- finalize: divide by l, write [b][n][h*64+d] ----
  for (int dt = 0; dt < 4; dt++)
    for (int r = 0; r < 4; r++) {
      float o = acc[dt][r] / lsum[r];
      int n = q0 + lk * 4 + r;
      attnb[((size_t)b * 2048 + n) * 1024 + h * 64 + dt * 16 + lrow] = f2b(o);
    }
}

extern "C" void kernel_launch(void* const* d_in, const int* in_sizes, int n_in,
                              void* d_out, int out_size, void* d_ws, size_t ws_size,
                              hipStream_t stream) {
  const float* x    = (const float*)d_in[0];
  const int*   mask = (const int*)d_in[1];
  const float* Wqkv = (const float*)d_in[2];
  const float* Wout = (const float*)d_in[3];
  const float* bout = (const float*)d_in[4];
  float* out = (float*)d_out;

  char* ws = (char*)d_ws;
  // layout (bytes): [0,8M) xb (later reused as attnb); [8M,14M) Wqkv_t (later Wout_t);
  // [14M,22M) Qb; [22M,30M) Kb; [30M,38M) Vt
  u16* xb     = (u16*)(ws);
  u16* attnb  = xb;                          // reused after gemm_qkv consumed xb
  u16* Wqkv_t = (u16*)(ws + (size_t)(8u << 20));
  u16* Wout_t = Wqkv_t;                      // reused after gemm_qkv consumed Wqkv_t
  u16* Qb     = (u16*)(ws + (size_t)(14u << 20));
  u16* Kb     = (u16*)(ws + (size_t)(22u << 20));
  u16* Vt     = (u16*)(ws + (size_t)(30u << 20));

  // 1) cast x -> bf16
  cast_bf16_kernel<<<4096, 256, 0, stream>>>(x, xb, 4096 * 1024 / 4);
  // 2) transpose-cast W_qkv [1024][3072] -> [3072][1024]
  transpose_cast_kernel<<<dim3(96, 32), dim3(32, 8), 0, stream>>>(Wqkv, Wqkv_t, 1024, 3072);
  // 3) QKV GEMM + head-split scatter (Vt transposed)
  gemm_qkv_kernel<<<dim3(24, 32), 256, 0, stream>>>(xb, Wqkv_t, Qb, Kb, Vt);
  // 4) transpose-cast W_out (into region no longer needed)
  transpose_cast_kernel<<<dim3(32, 32), dim3(32, 8), 0, stream>>>(Wout, Wout_t, 1024, 1024);
  // 5) flash attention
  attn_kernel<<<dim3(32, 32), 256, 0, stream>>>(Qb, Kb, Vt, mask, attnb);
  // 6) out projection + bias
  gemm_out_kernel<<<dim3(8, 32), 256, 0, stream>>>(attnb, Wout_t, bout, out);
}